// Round 1
// baseline (1330.529 us; speedup 1.0000x reference)
//
#include <hip/hip_runtime.h>
#include <math.h>

#define SLEN 2048
#define DMODEL 1024
#define NHEADS 16
#define DK 64
#define NBATCH 2

// ---------------------------------------------------------------------------
// GEMM: C = A[M,K] @ B[K,N]  (f32 row-major), 64x64 tile, BK=16, 4x4/thread.
// MODE 0: plain write C[m*N+n]                    (att @ Wo)
// MODE 1: RoPE(pos) then scatter to [B*H][S][DK]  (Q, K projections)
// MODE 2: scatter to [B*H][S][DK]                 (V projection)
// ---------------------------------------------------------------------------
template<int MODE>
__global__ __launch_bounds__(256)
void gemm64(const float* __restrict__ A, const float* __restrict__ B,
            float* __restrict__ C, const int* __restrict__ pos,
            int M, int N, int K)
{
    __shared__ float As[16][68];   // [k][m]  (A tile stored transposed)
    __shared__ float Bs[16][68];   // [k][n]
    const int tid = threadIdx.x;
    const int m0 = blockIdx.y << 6;
    const int n0 = blockIdx.x << 6;
    const int tx = tid & 15;       // col group (4 cols)
    const int ty = tid >> 4;       // row group (4 rows)
    const int ar = tid >> 2, ac = (tid & 3) << 2;   // A-tile load coords
    const int br = tid >> 4, bc = (tid & 15) << 2;  // B-tile load coords

    float acc[4][4];
    #pragma unroll
    for (int i = 0; i < 4; ++i)
        #pragma unroll
        for (int j = 0; j < 4; ++j) acc[i][j] = 0.f;

    for (int k0 = 0; k0 < K; k0 += 16) {
        float4 av = *reinterpret_cast<const float4*>(&A[(size_t)(m0 + ar) * K + (k0 + ac)]);
        float4 bv = *reinterpret_cast<const float4*>(&B[(size_t)(k0 + br) * N + (n0 + bc)]);
        As[ac + 0][ar] = av.x;
        As[ac + 1][ar] = av.y;
        As[ac + 2][ar] = av.z;
        As[ac + 3][ar] = av.w;
        *reinterpret_cast<float4*>(&Bs[br][bc]) = bv;
        __syncthreads();
        #pragma unroll
        for (int kk = 0; kk < 16; ++kk) {
            float4 a4 = *reinterpret_cast<const float4*>(&As[kk][ty << 2]);
            float4 b4 = *reinterpret_cast<const float4*>(&Bs[kk][tx << 2]);
            acc[0][0] += a4.x * b4.x; acc[0][1] += a4.x * b4.y;
            acc[0][2] += a4.x * b4.z; acc[0][3] += a4.x * b4.w;
            acc[1][0] += a4.y * b4.x; acc[1][1] += a4.y * b4.y;
            acc[1][2] += a4.y * b4.z; acc[1][3] += a4.y * b4.w;
            acc[2][0] += a4.z * b4.x; acc[2][1] += a4.z * b4.y;
            acc[2][2] += a4.z * b4.z; acc[2][3] += a4.z * b4.w;
            acc[3][0] += a4.w * b4.x; acc[3][1] += a4.w * b4.y;
            acc[3][2] += a4.w * b4.z; acc[3][3] += a4.w * b4.w;
        }
        __syncthreads();
    }

    if (MODE == 0) {
        #pragma unroll
        for (int i = 0; i < 4; ++i) {
            float4 v = make_float4(acc[i][0], acc[i][1], acc[i][2], acc[i][3]);
            *reinterpret_cast<float4*>(&C[(size_t)(m0 + ty * 4 + i) * N + (n0 + tx * 4)]) = v;
        }
    } else {
        #pragma unroll
        for (int i = 0; i < 4; ++i) {
            const int m = m0 + ty * 4 + i;
            const int b = m / SLEN, s = m % SLEN;
            #pragma unroll
            for (int jp = 0; jp < 2; ++jp) {
                const int n = n0 + tx * 4 + jp * 2;   // even column of the pair
                const int h = n / DK;
                const int d = n % DK;                 // even
                float v0 = acc[i][jp * 2 + 0];
                float v1 = acc[i][jp * 2 + 1];
                float r0 = v0, r1 = v1;
                if (MODE == 1) {
                    const float p = (float)pos[m];
                    // freq = THETA^(-d/DK) = exp(-d/DK * ln(10000))
                    const float freq = expf((float)d * (-9.210340371976184f / (float)DK));
                    float sn, cs;
                    sincosf(p * freq, &sn, &cs);
                    r0 = v0 * cs - v1 * sn;
                    r1 = v0 * sn + v1 * cs;
                }
                float* outp = &C[((size_t)(b * NHEADS + h) * SLEN + s) * DK + d];
                outp[0] = r0;
                outp[1] = r1;
            }
        }
    }
}

// ---------------------------------------------------------------------------
// Causal flash attention, f32. Block = 64 q-rows of one (b,h); 256 threads.
// Thread (r = tid/4, g = tid%4) owns q-row r: 16 interleaved score cols
// (c = cj*4+g — interleaving keeps Ks reads on distinct banks) and 16
// contiguous output dims (d = g*16..+15) for coalesced stores.
// Q,K,V layout: [B*H][S][DK]. Output written as [B][S][D_MODEL].
// ---------------------------------------------------------------------------
__global__ __launch_bounds__(256)
void attn64(const float* __restrict__ Q, const float* __restrict__ K,
            const float* __restrict__ V, float* __restrict__ O)
{
    __shared__ float Qs[64][68];
    __shared__ float Ks[64][68];
    __shared__ float Vs[64][68];
    __shared__ float Ps[64][68];
    const int tid = threadIdx.x;
    const int qt = blockIdx.x;     // q tile: 0..31
    const int bh = blockIdx.y;     // b*NHEADS + h: 0..31
    const size_t base = (size_t)bh * SLEN * DK;
    const int lr = tid >> 4, lc = (tid & 15) << 2;

    #pragma unroll
    for (int rr = 0; rr < 4; ++rr) {
        int row = rr * 16 + lr;
        *reinterpret_cast<float4*>(&Qs[row][lc]) =
            *reinterpret_cast<const float4*>(&Q[base + (size_t)(qt * 64 + row) * DK + lc]);
    }

    const int r = tid >> 2, g = tid & 3;
    float m = -1e30f, l = 0.f;
    float o[16];
    #pragma unroll
    for (int d = 0; d < 16; ++d) o[d] = 0.f;

    for (int kt = 0; kt <= qt; ++kt) {
        #pragma unroll
        for (int rr = 0; rr < 4; ++rr) {
            int row = rr * 16 + lr;
            *reinterpret_cast<float4*>(&Ks[row][lc]) =
                *reinterpret_cast<const float4*>(&K[base + (size_t)(kt * 64 + row) * DK + lc]);
            *reinterpret_cast<float4*>(&Vs[row][lc]) =
                *reinterpret_cast<const float4*>(&V[base + (size_t)(kt * 64 + row) * DK + lc]);
        }
        __syncthreads();

        float sc[16];
        #pragma unroll
        for (int cj = 0; cj < 16; ++cj) sc[cj] = 0.f;
        #pragma unroll 4
        for (int k4 = 0; k4 < 16; ++k4) {
            float4 q4 = *reinterpret_cast<const float4*>(&Qs[r][k4 << 2]);
            #pragma unroll
            for (int cj = 0; cj < 16; ++cj) {
                const int c = (cj << 2) + g;
                float4 kv = *reinterpret_cast<const float4*>(&Ks[c][k4 << 2]);
                sc[cj] += q4.x * kv.x + q4.y * kv.y + q4.z * kv.z + q4.w * kv.w;
            }
        }

        const bool diag = (kt == qt);
        float mloc = -1e30f;
        #pragma unroll
        for (int cj = 0; cj < 16; ++cj) {
            const int c = (cj << 2) + g;
            const bool valid = !diag || (c <= r);
            sc[cj] = valid ? sc[cj] * 0.125f : -1e30f;
            mloc = fmaxf(mloc, sc[cj]);
        }
        mloc = fmaxf(mloc, __shfl_xor(mloc, 1));
        mloc = fmaxf(mloc, __shfl_xor(mloc, 2));
        const float mnew = fmaxf(m, mloc);
        const float corr = __expf(m - mnew);
        float psum = 0.f;
        #pragma unroll
        for (int cj = 0; cj < 16; ++cj) {
            const float p = __expf(sc[cj] - mnew);
            psum += p;
            Ps[r][(cj << 2) + g] = p;
        }
        psum += __shfl_xor(psum, 1);
        psum += __shfl_xor(psum, 2);
        l = l * corr + psum;
        m = mnew;
        #pragma unroll
        for (int d = 0; d < 16; ++d) o[d] *= corr;
        __syncthreads();   // Ps visible to all (cross-lane safety)

        #pragma unroll 8
        for (int kk = 0; kk < 64; ++kk) {
            const float p = Ps[r][kk];
            #pragma unroll
            for (int d4 = 0; d4 < 4; ++d4) {
                float4 v = *reinterpret_cast<const float4*>(&Vs[kk][(g << 4) + (d4 << 2)]);
                o[d4 * 4 + 0] += p * v.x;
                o[d4 * 4 + 1] += p * v.y;
                o[d4 * 4 + 2] += p * v.z;
                o[d4 * 4 + 3] += p * v.w;
            }
        }
        __syncthreads();   // protect Ks/Vs/Ps before next iteration
    }

    const float inv = 1.f / l;
    const int b = bh >> 4, h = bh & 15;
    const int sg = (qt << 6) + r;
    float* outp = &O[((size_t)(b * SLEN + sg)) * DMODEL + (h * DK) + (g << 4)];
    #pragma unroll
    for (int d4 = 0; d4 < 4; ++d4) {
        float4 v = make_float4(o[d4 * 4 + 0] * inv, o[d4 * 4 + 1] * inv,
                               o[d4 * 4 + 2] * inv, o[d4 * 4 + 3] * inv);
        *reinterpret_cast<float4*>(&outp[d4 << 2]) = v;
    }
}

extern "C" void kernel_launch(void* const* d_in, const int* in_sizes, int n_in,
                              void* d_out, int out_size, void* d_ws, size_t ws_size,
                              hipStream_t stream)
{
    const float* x  = (const float*)d_in[0];
    const float* Wq = (const float*)d_in[1];
    const float* Wk = (const float*)d_in[2];
    const float* Wv = (const float*)d_in[3];
    const float* Wo = (const float*)d_in[4];
    const int*  pos = (const int*)d_in[5];
    float* out = (float*)d_out;

    const int M = NBATCH * SLEN;            // 4096
    const size_t mat = (size_t)M * DMODEL;  // 4,194,304 floats each
    float* Qws = (float*)d_ws;              // [B*H][S][DK]
    float* Kws = Qws + mat;
    float* Vws = Kws + mat;
    float* att = Vws + mat;                 // [B][S][D_MODEL]  (needs 64 MB ws total)

    dim3 gg(DMODEL / 64, M / 64);           // (16, 64)
    gemm64<1><<<gg, 256, 0, stream>>>(x, Wq, Qws, pos, M, DMODEL, DMODEL);
    gemm64<1><<<gg, 256, 0, stream>>>(x, Wk, Kws, pos, M, DMODEL, DMODEL);
    gemm64<2><<<gg, 256, 0, stream>>>(x, Wv, Vws, nullptr, M, DMODEL, DMODEL);

    dim3 ga(SLEN / 64, NBATCH * NHEADS);    // (32, 32)
    attn64<<<ga, 256, 0, stream>>>(Qws, Kws, Vws, att);

    gemm64<0><<<gg, 256, 0, stream>>>(att, Wo, out, nullptr, M, DMODEL, DMODEL);
}

// Round 2
// 203.296 us; speedup vs baseline: 6.5448x; 6.5448x over previous
//
#include <hip/hip_runtime.h>
#include <math.h>

#define SLEN 2048
#define DMODEL 1024
#define NHEADS 16
#define DK 64
#define NBATCH 2
#define M_TOT (NBATCH * SLEN)   // 4096
#define NQKV (3 * DMODEL)       // 3072

typedef __bf16 bf16x8 __attribute__((ext_vector_type(8)));
typedef float f32x4 __attribute__((ext_vector_type(4)));

// f32 -> bf16 round-to-nearest-even
static __device__ __forceinline__ unsigned short f2bf(float f) {
    unsigned int u = __float_as_uint(f);
    u += 0x7fffu + ((u >> 16) & 1u);
    return (unsigned short)(u >> 16);
}

// async global->LDS, 16 B per lane. lds dest is wave-uniform base + lane*16.
static __device__ __forceinline__ void gload16(const void* g, void* l) {
    __builtin_amdgcn_global_load_lds(
        (const __attribute__((address_space(1))) unsigned int*)g,
        (__attribute__((address_space(3))) unsigned int*)l, 16, 0, 0);
}

// ---------------------------------------------------------------------------
// x f32 -> bf16 (flat copy)
// ---------------------------------------------------------------------------
__global__ __launch_bounds__(256)
void convert_bf16(const float* __restrict__ X, unsigned short* __restrict__ Xb, int n4)
{
    int i = blockIdx.x * 256 + threadIdx.x;
    if (i < n4) {
        float4 v = *(const float4*)&X[(size_t)i * 4];
        ushort4 o;
        o.x = f2bf(v.x); o.y = f2bf(v.y); o.z = f2bf(v.z); o.w = f2bf(v.w);
        *(ushort4*)&Xb[(size_t)i * 4] = o;
    }
}

// ---------------------------------------------------------------------------
// W [1024][1024] f32 -> Wt [N][K] bf16 (transposed, so K is contiguous)
// ---------------------------------------------------------------------------
__global__ __launch_bounds__(256)
void transpose_w(const float* __restrict__ W, unsigned short* __restrict__ Wt)
{
    __shared__ float t[64][65];
    const int tid = threadIdx.x;
    const int c0 = blockIdx.x * 64, r0 = blockIdx.y * 64;
    const int tr = tid >> 4, tc = (tid & 15) * 4;
    #pragma unroll
    for (int rr = 0; rr < 4; ++rr) {
        int row = rr * 16 + tr;
        float4 v = *(const float4*)&W[(size_t)(r0 + row) * DMODEL + c0 + tc];
        t[row][tc + 0] = v.x; t[row][tc + 1] = v.y;
        t[row][tc + 2] = v.z; t[row][tc + 3] = v.w;
    }
    __syncthreads();
    #pragma unroll
    for (int rr = 0; rr < 4; ++rr) {
        int orow = rr * 16 + tr;  // n - c0
        ushort4 o;
        o.x = f2bf(t[tc + 0][orow]);
        o.y = f2bf(t[tc + 1][orow]);
        o.z = f2bf(t[tc + 2][orow]);
        o.w = f2bf(t[tc + 3][orow]);
        *(ushort4*)&Wt[(size_t)(c0 + orow) * DMODEL + r0 + tc] = o;
    }
}

// ---------------------------------------------------------------------------
// bf16 MFMA GEMM: C[M,N] = A[M,K] @ Bt[N,K]^T.  BM=BN=128, BK=64, 4 waves.
// LDS 16B-slot swizzle: phys slot p of row r holds logical slot p^(r&7);
// staging pre-swizzles the GLOBAL source so the LDS dest stays lane-linear.
// MODE 0: C f32 [M][N]          (att @ Wo -> d_out)
// MODE 1: N=3072 QKV fused; Q,K: RoPE -> [bh][s][64] bf16; V -> [bh][64][s]
// ---------------------------------------------------------------------------
template<int MODE>
__global__ __launch_bounds__(256)
void gemm_mfma(const unsigned short* __restrict__ A,
               const unsigned short* __restrict__ Bt,
               float* __restrict__ C,
               unsigned short* __restrict__ Qd,
               unsigned short* __restrict__ Kd,
               unsigned short* __restrict__ Vtd,
               const int* __restrict__ pos,
               int N, int K)
{
    __shared__ unsigned short As[128 * 64];
    __shared__ unsigned short Bs[128 * 64];
    const int tid = threadIdx.x;
    const int w = tid >> 6, l = tid & 63;
    const int m0 = blockIdx.y * 128, n0 = blockIdx.x * 128;
    const int wr = (w >> 1) * 64, wc = (w & 1) * 64;
    const int lr = l >> 3, lp = l & 7;

    f32x4 acc[4][4] = {};

    for (int k0 = 0; k0 < K; k0 += 64) {
        #pragma unroll
        for (int i = 0; i < 4; ++i) {
            int row = w * 32 + i * 8 + lr;
            int s = lp ^ (row & 7);
            gload16(A  + (size_t)(m0 + row) * K + k0 + s * 8, (void*)(As + (w * 32 + i * 8) * 64));
            gload16(Bt + (size_t)(n0 + row) * K + k0 + s * 8, (void*)(Bs + (w * 32 + i * 8) * 64));
        }
        __syncthreads();
        #pragma unroll
        for (int ks = 0; ks < 2; ++ks) {
            bf16x8 af[4], bfr[4];
            #pragma unroll
            for (int i = 0; i < 4; ++i) {
                int row = wr + i * 16 + (l & 15);
                int slot = (ks * 4 + (l >> 4)) ^ (row & 7);
                af[i] = *(const bf16x8*)((const char*)As + row * 128 + slot * 16);
            }
            #pragma unroll
            for (int j = 0; j < 4; ++j) {
                int row = wc + j * 16 + (l & 15);
                int slot = (ks * 4 + (l >> 4)) ^ (row & 7);
                bfr[j] = *(const bf16x8*)((const char*)Bs + row * 128 + slot * 16);
            }
            #pragma unroll
            for (int i = 0; i < 4; ++i)
                #pragma unroll
                for (int j = 0; j < 4; ++j)
                    acc[i][j] = __builtin_amdgcn_mfma_f32_16x16x32_bf16(af[i], bfr[j], acc[i][j], 0, 0, 0);
        }
        __syncthreads();
    }

    // Epilogue. C/D layout: col = lane&15, row = (lane>>4)*4 + reg.
    if (MODE == 0) {
        #pragma unroll
        for (int i = 0; i < 4; ++i)
            #pragma unroll
            for (int j = 0; j < 4; ++j)
                #pragma unroll
                for (int r = 0; r < 4; ++r) {
                    int row = m0 + wr + i * 16 + (l >> 4) * 4 + r;
                    int col = n0 + wc + j * 16 + (l & 15);
                    C[(size_t)row * N + col] = acc[i][j][r];
                }
    } else {
        const int seg = (n0 + wc) >> 10;  // 0=Q 1=K 2=V (block-uniform)
        #pragma unroll
        for (int i = 0; i < 4; ++i) {
            const int mbase = m0 + wr + i * 16 + (l >> 4) * 4;
            #pragma unroll
            for (int j = 0; j < 4; ++j) {
                const int n = n0 + wc + j * 16 + (l & 15);
                const int h = (n >> 6) & 15;
                const int d = n & 63;
                if (seg < 2) {
                    unsigned short* dst = (seg == 0) ? Qd : Kd;
                    const int de = d & ~1;
                    const float freq = __expf((float)de * (-9.210340371976184f / 64.f));
                    #pragma unroll
                    for (int r = 0; r < 4; ++r) {
                        const int m = mbase + r;
                        const int b = m >> 11, s = m & 2047;
                        float v = acc[i][j][r];
                        float p2 = __shfl_xor(v, 1);   // partner column of the RoPE pair
                        float ang = (float)pos[m] * freq;
                        float sn, cs;
                        __sincosf(ang, &sn, &cs);
                        float res = ((l & 1) == 0) ? (v * cs - p2 * sn) : (p2 * sn + v * cs);
                        dst[((size_t)(b * NHEADS + h) * SLEN + s) * DK + d] = f2bf(res);
                    }
                } else {
                    const int b = mbase >> 11, s0 = mbase & 2047;
                    ushort4 o;
                    o.x = f2bf(acc[i][j][0]); o.y = f2bf(acc[i][j][1]);
                    o.z = f2bf(acc[i][j][2]); o.w = f2bf(acc[i][j][3]);
                    *(ushort4*)&Vtd[((size_t)(b * NHEADS + h) * DK + d) * SLEN + s0] = o;
                }
            }
        }
    }
}

// ---------------------------------------------------------------------------
// MFMA flash attention. Block = 64 q-rows of one (b,h); 4 waves, wave w owns
// q-rows w*16..+15. KV tile = 64. K in LDS [kpos][64dk], V^T in LDS [d][64kpos],
// both XOR-swizzled; P staged per-wave in LDS for the PV A-operand.
// ---------------------------------------------------------------------------
__global__ __launch_bounds__(256)
void attn_mfma(const unsigned short* __restrict__ Q,
               const unsigned short* __restrict__ K,
               const unsigned short* __restrict__ Vt,
               unsigned short* __restrict__ Oa)
{
    __shared__ unsigned short Ks[64 * 64];
    __shared__ unsigned short Vs[64 * 64];
    __shared__ unsigned short Ps[4][16 * 64];
    const int tid = threadIdx.x;
    const int w = tid >> 6, l = tid & 63;
    // XCD-bijective swizzle: XCD x gets bh in [4x, 4x+4) -> 2 MB K/V per L2.
    const int id = blockIdx.x;
    const int nid = (id & 7) * 128 + (id >> 3);
    const int bh = nid >> 5, qt = nid & 31;
    const unsigned short* Qb = Q + (size_t)bh * SLEN * DK;
    const unsigned short* Kb = K + (size_t)bh * SLEN * DK;
    const unsigned short* Vb = Vt + (size_t)bh * DK * SLEN;
    const int lr = l >> 3, lp = l & 7;

    const int q0 = qt * 64 + w * 16;
    bf16x8 qf[2];
    #pragma unroll
    for (int ks = 0; ks < 2; ++ks)
        qf[ks] = *(const bf16x8*)(Qb + (size_t)(q0 + (l & 15)) * DK + ks * 32 + (l >> 4) * 8);

    float mrow[4], lrowv[4];
    f32x4 oacc[4] = {};
    #pragma unroll
    for (int r = 0; r < 4; ++r) { mrow[r] = -1e30f; lrowv[r] = 0.f; }
    const int qrow_g = qt * 64 + w * 16 + (l >> 4) * 4;  // + r

    for (int kt = 0; kt <= qt; ++kt) {
        #pragma unroll
        for (int i = 0; i < 2; ++i) {
            int row = w * 16 + i * 8 + lr;
            int s = lp ^ (row & 7);
            gload16(Kb + (size_t)(kt * 64 + row) * DK + s * 8, (void*)(Ks + (w * 16 + i * 8) * 64));
            gload16(Vb + (size_t)row * SLEN + kt * 64 + s * 8, (void*)(Vs + (w * 16 + i * 8) * 64));
        }
        __syncthreads();

        // S = Q K^T
        f32x4 sacc[4] = {};
        #pragma unroll
        for (int ks = 0; ks < 2; ++ks)
            #pragma unroll
            for (int cb = 0; cb < 4; ++cb) {
                int row = cb * 16 + (l & 15);
                int slot = (ks * 4 + (l >> 4)) ^ (row & 7);
                bf16x8 kf = *(const bf16x8*)((const char*)Ks + row * 128 + slot * 16);
                sacc[cb] = __builtin_amdgcn_mfma_f32_16x16x32_bf16(qf[ks], kf, sacc[cb], 0, 0, 0);
            }

        // online softmax (row r held by the 16 lanes with same l>>4)
        #pragma unroll
        for (int r = 0; r < 4; ++r) {
            float sc[4];
            float mx = -1e30f;
            #pragma unroll
            for (int cb = 0; cb < 4; ++cb) {
                int kg = kt * 64 + cb * 16 + (l & 15);
                float v = sacc[cb][r] * 0.125f;
                sc[cb] = (kg <= qrow_g + r) ? v : -1e30f;
                mx = fmaxf(mx, sc[cb]);
            }
            mx = fmaxf(mx, __shfl_xor(mx, 1));
            mx = fmaxf(mx, __shfl_xor(mx, 2));
            mx = fmaxf(mx, __shfl_xor(mx, 4));
            mx = fmaxf(mx, __shfl_xor(mx, 8));
            float mn = fmaxf(mrow[r], mx);
            float corr = __expf(mrow[r] - mn);
            mrow[r] = mn;
            float ps = 0.f;
            const int row_loc = (l >> 4) * 4 + r;
            #pragma unroll
            for (int cb = 0; cb < 4; ++cb) {
                float p = __expf(sc[cb] - mn);
                ps += p;
                int col = cb * 16 + (l & 15);
                int byte = row_loc * 128 + ((col * 2) ^ ((row_loc & 7) << 4));
                *(unsigned short*)((char*)Ps[w] + byte) = f2bf(p);
            }
            ps += __shfl_xor(ps, 1);
            ps += __shfl_xor(ps, 2);
            ps += __shfl_xor(ps, 4);
            ps += __shfl_xor(ps, 8);
            lrowv[r] = lrowv[r] * corr + ps;
            #pragma unroll
            for (int db = 0; db < 4; ++db) oacc[db][r] *= corr;
        }

        // O += P V
        #pragma unroll
        for (int ks = 0; ks < 2; ++ks) {
            const int prow = l & 15;
            const int pslot = (ks * 4 + (l >> 4)) ^ (prow & 7);
            bf16x8 pf = *(const bf16x8*)((const char*)Ps[w] + prow * 128 + pslot * 16);
            #pragma unroll
            for (int db = 0; db < 4; ++db) {
                int row = db * 16 + (l & 15);
                int slot = (ks * 4 + (l >> 4)) ^ (row & 7);
                bf16x8 vf = *(const bf16x8*)((const char*)Vs + row * 128 + slot * 16);
                oacc[db] = __builtin_amdgcn_mfma_f32_16x16x32_bf16(pf, vf, oacc[db], 0, 0, 0);
            }
        }
        __syncthreads();
    }

    const int b = bh >> 4, h = bh & 15;
    #pragma unroll
    for (int r = 0; r < 4; ++r) {
        float inv = 1.f / lrowv[r];
        int srow = qt * 64 + w * 16 + (l >> 4) * 4 + r;
        #pragma unroll
        for (int db = 0; db < 4; ++db)
            Oa[(size_t)(b * SLEN + srow) * DMODEL + h * DK + db * 16 + (l & 15)] =
                f2bf(oacc[db][r] * inv);
    }
}

extern "C" void kernel_launch(void* const* d_in, const int* in_sizes, int n_in,
                              void* d_out, int out_size, void* d_ws, size_t ws_size,
                              hipStream_t stream)
{
    const float* x  = (const float*)d_in[0];
    const float* Wq = (const float*)d_in[1];
    const float* Wk = (const float*)d_in[2];
    const float* Wv = (const float*)d_in[3];
    const float* Wo = (const float*)d_in[4];
    const int*  pos = (const int*)d_in[5];
    float* out = (float*)d_out;

    char* ws = (char*)d_ws;
    const size_t MB = 1024 * 1024;
    unsigned short* xb   = (unsigned short*)(ws);             // 8 MB  [4096][1024]
    unsigned short* Wcat = (unsigned short*)(ws + 8 * MB);    // 6 MB  [3072][1024]
    unsigned short* Wot  = (unsigned short*)(ws + 14 * MB);   // 2 MB  [1024][1024]
    unsigned short* Qws  = (unsigned short*)(ws + 16 * MB);   // 8 MB  [32][2048][64]
    unsigned short* Kws  = (unsigned short*)(ws + 24 * MB);   // 8 MB  [32][2048][64]
    unsigned short* Vtws = (unsigned short*)(ws + 32 * MB);   // 8 MB  [32][64][2048]
    unsigned short* attb = (unsigned short*)(ws + 40 * MB);   // 8 MB  [4096][1024]

    convert_bf16<<<4096, 256, 0, stream>>>(x, xb, M_TOT * DMODEL / 4);
    transpose_w<<<dim3(16, 16), 256, 0, stream>>>(Wq, Wcat);
    transpose_w<<<dim3(16, 16), 256, 0, stream>>>(Wk, Wcat + 1024 * 1024);
    transpose_w<<<dim3(16, 16), 256, 0, stream>>>(Wv, Wcat + 2 * 1024 * 1024);
    transpose_w<<<dim3(16, 16), 256, 0, stream>>>(Wo, Wot);

    gemm_mfma<1><<<dim3(NQKV / 128, M_TOT / 128), 256, 0, stream>>>(
        xb, Wcat, nullptr, Qws, Kws, Vtws, pos, NQKV, DMODEL);

    attn_mfma<<<1024, 256, 0, stream>>>(Qws, Kws, Vtws, attb);

    gemm_mfma<0><<<dim3(DMODEL / 128, M_TOT / 128), 256, 0, stream>>>(
        attb, Wot, out, nullptr, nullptr, nullptr, nullptr, DMODEL, DMODEL);
}

// Round 3
// 160.708 us; speedup vs baseline: 8.2792x; 1.2650x over previous
//
#include <hip/hip_runtime.h>
#include <math.h>

#define SLEN 2048
#define DMODEL 1024
#define NHEADS 16
#define DK 64
#define NBATCH 2
#define M_TOT (NBATCH * SLEN)   // 4096
#define NQKV (3 * DMODEL)       // 3072
#define KVB 128

typedef __bf16 bf16x8 __attribute__((ext_vector_type(8)));
typedef float f32x4 __attribute__((ext_vector_type(4)));

// f32 -> bf16 round-to-nearest-even
static __device__ __forceinline__ unsigned short f2bf(float f) {
    unsigned int u = __float_as_uint(f);
    u += 0x7fffu + ((u >> 16) & 1u);
    return (unsigned short)(u >> 16);
}

// pack two f32 -> bf16x2 dword (lo = a, hi = b)
static __device__ __forceinline__ unsigned cvtpk(float a, float b) {
    unsigned r;
    asm("v_cvt_pk_bf16_f32 %0, %1, %2" : "=v"(r) : "v"(a), "v"(b));
    return r;
}

#if __has_builtin(__builtin_amdgcn_exp2f)
#define EXP2(x) __builtin_amdgcn_exp2f(x)
#else
#define EXP2(x) exp2f(x)
#endif

// async global->LDS, 16 B per lane. lds dest is wave-uniform base + lane*16.
static __device__ __forceinline__ void gload16(const void* g, void* l) {
    __builtin_amdgcn_global_load_lds(
        (const __attribute__((address_space(1))) unsigned int*)g,
        (__attribute__((address_space(3))) unsigned int*)l, 16, 0, 0);
}

// ---------------------------------------------------------------------------
// x f32 -> bf16 (flat copy)
// ---------------------------------------------------------------------------
__global__ __launch_bounds__(256)
void convert_bf16(const float* __restrict__ X, unsigned short* __restrict__ Xb, int n4)
{
    int i = blockIdx.x * 256 + threadIdx.x;
    if (i < n4) {
        float4 v = *(const float4*)&X[(size_t)i * 4];
        ushort4 o;
        o.x = f2bf(v.x); o.y = f2bf(v.y); o.z = f2bf(v.z); o.w = f2bf(v.w);
        *(ushort4*)&Xb[(size_t)i * 4] = o;
    }
}

// ---------------------------------------------------------------------------
// W [1024][1024] f32 -> Wt [N][K] bf16 (transposed, so K is contiguous)
// ---------------------------------------------------------------------------
__global__ __launch_bounds__(256)
void transpose_w(const float* __restrict__ W, unsigned short* __restrict__ Wt)
{
    __shared__ float t[64][65];
    const int tid = threadIdx.x;
    const int c0 = blockIdx.x * 64, r0 = blockIdx.y * 64;
    const int tr = tid >> 4, tc = (tid & 15) * 4;
    #pragma unroll
    for (int rr = 0; rr < 4; ++rr) {
        int row = rr * 16 + tr;
        float4 v = *(const float4*)&W[(size_t)(r0 + row) * DMODEL + c0 + tc];
        t[row][tc + 0] = v.x; t[row][tc + 1] = v.y;
        t[row][tc + 2] = v.z; t[row][tc + 3] = v.w;
    }
    __syncthreads();
    #pragma unroll
    for (int rr = 0; rr < 4; ++rr) {
        int orow = rr * 16 + tr;
        ushort4 o;
        o.x = f2bf(t[tc + 0][orow]);
        o.y = f2bf(t[tc + 1][orow]);
        o.z = f2bf(t[tc + 2][orow]);
        o.w = f2bf(t[tc + 3][orow]);
        *(ushort4*)&Wt[(size_t)(c0 + orow) * DMODEL + r0 + tc] = o;
    }
}

// ---------------------------------------------------------------------------
// bf16 MFMA GEMM: C[M,N] = A[M,K] @ Bt[N,K]^T.  BM=BN=128, BK=64, 4 waves.
// MODE 0: C f32 [M][N]          (att @ Wo -> d_out)
// MODE 1: N=3072 QKV fused; Q,K: RoPE; Q scaled by 0.125*log2e -> [bh][s][64];
//         V -> [bh][64][s] (transposed)
// ---------------------------------------------------------------------------
template<int MODE>
__global__ __launch_bounds__(256)
void gemm_mfma(const unsigned short* __restrict__ A,
               const unsigned short* __restrict__ Bt,
               float* __restrict__ C,
               unsigned short* __restrict__ Qd,
               unsigned short* __restrict__ Kd,
               unsigned short* __restrict__ Vtd,
               const int* __restrict__ pos,
               int N, int K)
{
    __shared__ unsigned short As[128 * 64];
    __shared__ unsigned short Bs[128 * 64];
    const int tid = threadIdx.x;
    const int w = tid >> 6, l = tid & 63;
    const int m0 = blockIdx.y * 128, n0 = blockIdx.x * 128;
    const int wr = (w >> 1) * 64, wc = (w & 1) * 64;
    const int lr = l >> 3, lp = l & 7;

    f32x4 acc[4][4] = {};

    for (int k0 = 0; k0 < K; k0 += 64) {
        #pragma unroll
        for (int i = 0; i < 4; ++i) {
            int row = w * 32 + i * 8 + lr;
            int s = lp ^ (row & 7);
            gload16(A  + (size_t)(m0 + row) * K + k0 + s * 8, (void*)(As + (w * 32 + i * 8) * 64));
            gload16(Bt + (size_t)(n0 + row) * K + k0 + s * 8, (void*)(Bs + (w * 32 + i * 8) * 64));
        }
        __syncthreads();
        #pragma unroll
        for (int ks = 0; ks < 2; ++ks) {
            bf16x8 af[4], bfr[4];
            #pragma unroll
            for (int i = 0; i < 4; ++i) {
                int row = wr + i * 16 + (l & 15);
                int slot = (ks * 4 + (l >> 4)) ^ (row & 7);
                af[i] = *(const bf16x8*)((const char*)As + row * 128 + slot * 16);
            }
            #pragma unroll
            for (int j = 0; j < 4; ++j) {
                int row = wc + j * 16 + (l & 15);
                int slot = (ks * 4 + (l >> 4)) ^ (row & 7);
                bfr[j] = *(const bf16x8*)((const char*)Bs + row * 128 + slot * 16);
            }
            #pragma unroll
            for (int i = 0; i < 4; ++i)
                #pragma unroll
                for (int j = 0; j < 4; ++j)
                    acc[i][j] = __builtin_amdgcn_mfma_f32_16x16x32_bf16(af[i], bfr[j], acc[i][j], 0, 0, 0);
        }
        __syncthreads();
    }

    // Epilogue. C/D layout: col = lane&15, row = (lane>>4)*4 + reg.
    if (MODE == 0) {
        #pragma unroll
        for (int i = 0; i < 4; ++i)
            #pragma unroll
            for (int j = 0; j < 4; ++j)
                #pragma unroll
                for (int r = 0; r < 4; ++r) {
                    int row = m0 + wr + i * 16 + (l >> 4) * 4 + r;
                    int col = n0 + wc + j * 16 + (l & 15);
                    C[(size_t)row * N + col] = acc[i][j][r];
                }
    } else {
        const int seg = (n0 + wc) >> 10;  // 0=Q 1=K 2=V (block-uniform)
        #pragma unroll
        for (int i = 0; i < 4; ++i) {
            const int mbase = m0 + wr + i * 16 + (l >> 4) * 4;
            #pragma unroll
            for (int j = 0; j < 4; ++j) {
                const int n = n0 + wc + j * 16 + (l & 15);
                const int h = (n >> 6) & 15;
                const int d = n & 63;
                if (seg < 2) {
                    unsigned short* dst = (seg == 0) ? Qd : Kd;
                    const int de = d & ~1;
                    const float freq = __expf((float)de * (-9.210340371976184f / 64.f));
                    #pragma unroll
                    for (int r = 0; r < 4; ++r) {
                        const int m = mbase + r;
                        const int b = m >> 11, s = m & 2047;
                        float v = acc[i][j][r];
                        float p2 = __shfl_xor(v, 1);   // partner column of the RoPE pair
                        float ang = (float)pos[m] * freq;
                        float sn, cs;
                        __sincosf(ang, &sn, &cs);
                        float res = ((l & 1) == 0) ? (v * cs - p2 * sn) : (p2 * sn + v * cs);
                        if (seg == 0) res *= 0.18033688011112042f;  // 0.125*log2(e): exp2-domain softmax
                        dst[((size_t)(b * NHEADS + h) * SLEN + s) * DK + d] = f2bf(res);
                    }
                } else {
                    const int b = mbase >> 11, s0 = mbase & 2047;
                    ushort4 o;
                    o.x = f2bf(acc[i][j][0]); o.y = f2bf(acc[i][j][1]);
                    o.z = f2bf(acc[i][j][2]); o.w = f2bf(acc[i][j][3]);
                    *(ushort4*)&Vtd[((size_t)(b * NHEADS + h) * DK + d) * SLEN + s0] = o;
                }
            }
        }
    }
}

// ---------------------------------------------------------------------------
// MFMA flash attention v2: swapped QK^T (S^T), O^T-form PV, lane-local softmax.
// Block = 64 q-rows of one (b,h), 4 waves (wave w: q-cols w*16..+15), KV tile 128.
// Lane (g=l>>4, q15=l&15) owns full row q = qt*64 + w*16 + q15:
//   sacc[cb][r] = S[q][k = kt*128 + cb*16 + g*4 + r]
//   oacc[db][r] = O^T[d = db*16 + g*4 + r][q]
// P -> PV B-frag via cvt_pk + 8 shfl per ks2 (register exchange, no LDS P).
// ---------------------------------------------------------------------------
__global__ __launch_bounds__(256, 4)
void attn_mfma(const unsigned short* __restrict__ Q,
               const unsigned short* __restrict__ K,
               const unsigned short* __restrict__ Vt,
               unsigned short* __restrict__ Oa)
{
    __shared__ char smem[32768];
    unsigned short* Ks = (unsigned short*)smem;            // [128 kpos][64 dk]
    unsigned short* Vs = (unsigned short*)(smem + 16384);  // [64 d][128 kpos]
    const int tid = threadIdx.x;
    const int w = tid >> 6, l = tid & 63;
    const int g = l >> 4, q15 = l & 15;

    // bh-major; qt interleaved heavy/light for uniform retirement.
    const int id = blockIdx.x;
    const int bh = id >> 5;
    const int j = id & 31;
    const int qt = (j & 1) ? ((j - 1) >> 1) : (31 - (j >> 1));
    const int nkt = (qt + 2) >> 1;   // ceil((qt*64+64)/128)

    const unsigned short* Qb = Q + (size_t)bh * SLEN * DK;
    const unsigned short* Kb = K + (size_t)bh * SLEN * DK;
    const unsigned short* Vb = Vt + (size_t)bh * DK * SLEN;

    const int q0 = qt * 64 + w * 16;
    const int q_g = q0 + q15;

    bf16x8 qf[2];
    #pragma unroll
    for (int ks = 0; ks < 2; ++ks)
        qf[ks] = *(const bf16x8*)(Qb + (size_t)(q0 + q15) * DK + ks * 32 + g * 8);

    float m = -1e30f, lsum = 0.f;
    f32x4 oacc[4] = {};

    // P-exchange source lanes: dest dword t reads from group 2*(g&1) + (t>>1)
    const int srcA = q15 + 32 * (g & 1);
    const int srcB = srcA + 16;

    for (int kt = 0; kt < nkt; ++kt) {
        {   // stage K[128][64] and V^T[64][128], XOR-swizzled via global source
            const int lr8 = l >> 3, lp8 = l & 7;
            #pragma unroll
            for (int i = 0; i < 4; ++i) {
                int row = w * 32 + i * 8 + lr8;
                gload16(Kb + (size_t)(kt * KVB + row) * DK + ((lp8 ^ (row & 7)) * 8),
                        (void*)(Ks + (w * 32 + i * 8) * DK));
            }
            const int lr4 = l >> 4, lp16 = l & 15;
            #pragma unroll
            for (int i = 0; i < 4; ++i) {
                int row = w * 16 + i * 4 + lr4;
                gload16(Vb + (size_t)row * SLEN + kt * KVB + ((lp16 ^ (row & 7)) * 8),
                        (void*)(Vs + (w * 16 + i * 4) * KVB));
            }
        }
        __syncthreads();

        // S^T = K · Q (Q as B-operand): sacc[cb] rows = kpos, col = q
        f32x4 sacc[8] = {};
        __builtin_amdgcn_s_setprio(1);
        #pragma unroll
        for (int ks = 0; ks < 2; ++ks)
            #pragma unroll
            for (int cb = 0; cb < 8; ++cb) {
                int row = cb * 16 + q15;
                int slot = (ks * 4 + g) ^ (row & 7);
                bf16x8 kf = *(const bf16x8*)((const char*)Ks + row * 128 + slot * 16);
                sacc[cb] = __builtin_amdgcn_mfma_f32_16x16x32_bf16(kf, qf[ks], sacc[cb], 0, 0, 0);
            }
        __builtin_amdgcn_s_setprio(0);

        // causal mask: only the last tile can touch the diagonal
        if (kt == nkt - 1) {
            const int kb = kt * KVB + g * 4;
            #pragma unroll
            for (int cb = 0; cb < 8; ++cb)
                #pragma unroll
                for (int r = 0; r < 4; ++r)
                    if (kb + cb * 16 + r > q_g) sacc[cb][r] = -1e30f;
        }

        // lane-local softmax (scores already in log2 domain)
        float mx = -1e30f;
        #pragma unroll
        for (int cb = 0; cb < 8; ++cb)
            #pragma unroll
            for (int r = 0; r < 4; ++r) mx = fmaxf(mx, sacc[cb][r]);
        mx = fmaxf(mx, __shfl_xor(mx, 16));
        mx = fmaxf(mx, __shfl_xor(mx, 32));

        if (mx > m + 6.0f) {          // defer-max: skip rescale unless max grew
            float corr = EXP2(m - mx);
            m = mx;
            lsum *= corr;
            #pragma unroll
            for (int db = 0; db < 4; ++db)
                #pragma unroll
                for (int r = 0; r < 4; ++r) oacc[db][r] *= corr;
        }

        float ps = 0.f;
        #pragma unroll
        for (int cb = 0; cb < 8; ++cb)
            #pragma unroll
            for (int r = 0; r < 4; ++r) {
                float e = EXP2(sacc[cb][r] - m);
                sacc[cb][r] = e;
                ps += e;
            }
        ps += __shfl_xor(ps, 16);
        ps += __shfl_xor(ps, 32);
        lsum += ps;

        // pack P to bf16 dwords: pk[cb][u] = {P[k=cb*16+g*4+2u], [+1]}
        unsigned pk[8][2];
        #pragma unroll
        for (int cb = 0; cb < 8; ++cb) {
            pk[cb][0] = cvtpk(sacc[cb][0], sacc[cb][1]);
            pk[cb][1] = cvtpk(sacc[cb][2], sacc[cb][3]);
        }

        // O^T += V^T · P^T  (A = Vs rows d, B = P^T built by register exchange)
        #pragma unroll
        for (int ks2 = 0; ks2 < 4; ++ks2) {
            unsigned y0 = __shfl((int)pk[2 * ks2][0], srcA);
            unsigned y1 = __shfl((int)pk[2 * ks2][1], srcA);
            unsigned y2 = __shfl((int)pk[2 * ks2][0], srcB);
            unsigned y3 = __shfl((int)pk[2 * ks2][1], srcB);
            unsigned z0 = __shfl((int)pk[2 * ks2 + 1][0], srcA);
            unsigned z1 = __shfl((int)pk[2 * ks2 + 1][1], srcA);
            unsigned z2 = __shfl((int)pk[2 * ks2 + 1][0], srcB);
            unsigned z3 = __shfl((int)pk[2 * ks2 + 1][1], srcB);
            union { unsigned u[4]; bf16x8 v; } pf;
            const bool lo = (g < 2);
            pf.u[0] = lo ? y0 : z0;
            pf.u[1] = lo ? y1 : z1;
            pf.u[2] = lo ? y2 : z2;
            pf.u[3] = lo ? y3 : z3;
            __builtin_amdgcn_s_setprio(1);
            #pragma unroll
            for (int db = 0; db < 4; ++db) {
                int row = db * 16 + q15;
                int slot = (ks2 * 4 + g) ^ (row & 7);
                bf16x8 vf = *(const bf16x8*)((const char*)Vs + row * 256 + slot * 16);
                oacc[db] = __builtin_amdgcn_mfma_f32_16x16x32_bf16(vf, pf.v, oacc[db], 0, 0, 0);
            }
            __builtin_amdgcn_s_setprio(0);
        }
        __syncthreads();
    }

    // epilogue: O^T -> O via LDS transpose (Os aliases Ks; swizzled)
    unsigned short* Os = (unsigned short*)smem;   // [64 q][64 d]
    const float inv = 1.f / lsum;
    const int ql = w * 16 + q15;
    #pragma unroll
    for (int db = 0; db < 4; ++db)
        #pragma unroll
        for (int r = 0; r < 4; ++r) {
            int d = db * 16 + g * 4 + r;
            int byte = ql * 128 + ((d * 2) ^ ((ql & 7) << 4));
            *(unsigned short*)((char*)Os + byte) = f2bf(oacc[db][r] * inv);
        }
    __syncthreads();

    const int b = bh >> 4, h = bh & 15;
    #pragma unroll
    for (int i = 0; i < 2; ++i) {
        int qp = w * 16 + i * 8 + (l >> 3);
        int c = l & 7;
        uint4 vv = *(const uint4*)((const char*)Os + qp * 128 + ((c ^ (qp & 7)) << 4));
        int srow = qt * 64 + qp;
        *(uint4*)&Oa[((size_t)(b * SLEN + srow)) * DMODEL + h * DK + c * 8] = vv;
    }
}

extern "C" void kernel_launch(void* const* d_in, const int* in_sizes, int n_in,
                              void* d_out, int out_size, void* d_ws, size_t ws_size,
                              hipStream_t stream)
{
    const float* x  = (const float*)d_in[0];
    const float* Wq = (const float*)d_in[1];
    const float* Wk = (const float*)d_in[2];
    const float* Wv = (const float*)d_in[3];
    const float* Wo = (const float*)d_in[4];
    const int*  pos = (const int*)d_in[5];
    float* out = (float*)d_out;

    char* ws = (char*)d_ws;
    const size_t MB = 1024 * 1024;
    unsigned short* xb   = (unsigned short*)(ws);             // 8 MB
    unsigned short* Wcat = (unsigned short*)(ws + 8 * MB);    // 6 MB
    unsigned short* Wot  = (unsigned short*)(ws + 14 * MB);   // 2 MB
    unsigned short* Qws  = (unsigned short*)(ws + 16 * MB);   // 8 MB [32][2048][64]
    unsigned short* Kws  = (unsigned short*)(ws + 24 * MB);   // 8 MB [32][2048][64]
    unsigned short* Vtws = (unsigned short*)(ws + 32 * MB);   // 8 MB [32][64][2048]
    unsigned short* attb = (unsigned short*)(ws + 40 * MB);   // 8 MB [4096][1024]

    convert_bf16<<<4096, 256, 0, stream>>>(x, xb, M_TOT * DMODEL / 4);
    transpose_w<<<dim3(16, 16), 256, 0, stream>>>(Wq, Wcat);
    transpose_w<<<dim3(16, 16), 256, 0, stream>>>(Wk, Wcat + 1024 * 1024);
    transpose_w<<<dim3(16, 16), 256, 0, stream>>>(Wv, Wcat + 2 * 1024 * 1024);
    transpose_w<<<dim3(16, 16), 256, 0, stream>>>(Wo, Wot);

    gemm_mfma<1><<<dim3(NQKV / 128, M_TOT / 128), 256, 0, stream>>>(
        xb, Wcat, nullptr, Qws, Kws, Vtws, pos, NQKV, DMODEL);

    attn_mfma<<<1024, 256, 0, stream>>>(Qws, Kws, Vtws, attb);

    gemm_mfma<0><<<dim3(DMODEL / 128, M_TOT / 128), 256, 0, stream>>>(
        attb, Wot, out, nullptr, nullptr, nullptr, nullptr, DMODEL, DMODEL);
}

// Round 4
// 141.211 us; speedup vs baseline: 9.4223x; 1.1381x over previous
//
#include <hip/hip_runtime.h>
#include <math.h>

#define SLEN 2048
#define DMODEL 1024
#define NHEADS 16
#define DK 64
#define NBATCH 2
#define M_TOT (NBATCH * SLEN)   // 4096
#define NQKV (3 * DMODEL)       // 3072
#define KVB 128

typedef __bf16 bf16x8 __attribute__((ext_vector_type(8)));
typedef float f32x4 __attribute__((ext_vector_type(4)));

// f32 -> bf16 round-to-nearest-even
static __device__ __forceinline__ unsigned short f2bf(float f) {
    unsigned int u = __float_as_uint(f);
    u += 0x7fffu + ((u >> 16) & 1u);
    return (unsigned short)(u >> 16);
}

// pack two f32 -> bf16x2 dword (lo = a, hi = b)
static __device__ __forceinline__ unsigned cvtpk(float a, float b) {
    unsigned r;
    asm("v_cvt_pk_bf16_f32 %0, %1, %2" : "=v"(r) : "v"(a), "v"(b));
    return r;
}

#if __has_builtin(__builtin_amdgcn_exp2f)
#define EXP2(x) __builtin_amdgcn_exp2f(x)
#else
#define EXP2(x) exp2f(x)
#endif

// async global->LDS, 16 B per lane. lds dest is wave-uniform base + lane*16.
static __device__ __forceinline__ void gload16(const void* g, void* l) {
    __builtin_amdgcn_global_load_lds(
        (const __attribute__((address_space(1))) unsigned int*)g,
        (__attribute__((address_space(3))) unsigned int*)l, 16, 0, 0);
}

// ---------------------------------------------------------------------------
// x f32 -> bf16 (flat copy)
// ---------------------------------------------------------------------------
__global__ __launch_bounds__(256)
void convert_bf16(const float* __restrict__ X, unsigned short* __restrict__ Xb, int n4)
{
    int i = blockIdx.x * 256 + threadIdx.x;
    if (i < n4) {
        float4 v = *(const float4*)&X[(size_t)i * 4];
        ushort4 o;
        o.x = f2bf(v.x); o.y = f2bf(v.y); o.z = f2bf(v.z); o.w = f2bf(v.w);
        *(ushort4*)&Xb[(size_t)i * 4] = o;
    }
}

// ---------------------------------------------------------------------------
// W [1024][1024] f32 -> Wt [N][K] bf16 (transposed, so K is contiguous)
// ---------------------------------------------------------------------------
__global__ __launch_bounds__(256)
void transpose_w(const float* __restrict__ W, unsigned short* __restrict__ Wt)
{
    __shared__ float t[64][65];
    const int tid = threadIdx.x;
    const int c0 = blockIdx.x * 64, r0 = blockIdx.y * 64;
    const int tr = tid >> 4, tc = (tid & 15) * 4;
    #pragma unroll
    for (int rr = 0; rr < 4; ++rr) {
        int row = rr * 16 + tr;
        float4 v = *(const float4*)&W[(size_t)(r0 + row) * DMODEL + c0 + tc];
        t[row][tc + 0] = v.x; t[row][tc + 1] = v.y;
        t[row][tc + 2] = v.z; t[row][tc + 3] = v.w;
    }
    __syncthreads();
    #pragma unroll
    for (int rr = 0; rr < 4; ++rr) {
        int orow = rr * 16 + tr;
        ushort4 o;
        o.x = f2bf(t[tc + 0][orow]);
        o.y = f2bf(t[tc + 1][orow]);
        o.z = f2bf(t[tc + 2][orow]);
        o.w = f2bf(t[tc + 3][orow]);
        *(ushort4*)&Wt[(size_t)(c0 + orow) * DMODEL + r0 + tc] = o;
    }
}

// ---------------------------------------------------------------------------
// bf16 MFMA GEMM: C[M,N] = A[M,K] @ Bt[N,K]^T.  BM=BN=128, BK=64, 4 waves.
// Double-buffered LDS (T3-minimal 2-phase): STAGE(t+1) issued right after the
// single per-tile barrier; compute(t) overlaps the next tile's DMA flight.
// MODE 0: C f32 [M][N]          (att @ Wo -> d_out)
// MODE 1: N=3072 QKV fused; Q,K: RoPE; Q scaled by 0.125*log2e -> [bh][s][64];
//         V -> [bh][64][s] (transposed)
// ---------------------------------------------------------------------------
template<int MODE>
__global__ __launch_bounds__(256)
void gemm_mfma(const unsigned short* __restrict__ A,
               const unsigned short* __restrict__ Bt,
               float* __restrict__ C,
               unsigned short* __restrict__ Qd,
               unsigned short* __restrict__ Kd,
               unsigned short* __restrict__ Vtd,
               const int* __restrict__ pos,
               int N, int K)
{
    __shared__ unsigned short AB[2 * 2 * 128 * 64];   // [buf][A/B][128][64], 64 KB
    const int tid = threadIdx.x;
    const int w = tid >> 6, l = tid & 63;
    const int m0 = blockIdx.y * 128, n0 = blockIdx.x * 128;
    const int wr = (w >> 1) * 64, wc = (w & 1) * 64;
    const int lr = l >> 3, lp = l & 7;

    f32x4 acc[4][4] = {};

    auto STAGE = [&](int k0, int buf) {
        unsigned short* Asd = AB + buf * (2 * 128 * 64);
        unsigned short* Bsd = Asd + 128 * 64;
        #pragma unroll
        for (int i = 0; i < 4; ++i) {
            int row = w * 32 + i * 8 + lr;
            int s = lp ^ (row & 7);
            gload16(A  + (size_t)(m0 + row) * K + k0 + s * 8, (void*)(Asd + (w * 32 + i * 8) * 64));
            gload16(Bt + (size_t)(n0 + row) * K + k0 + s * 8, (void*)(Bsd + (w * 32 + i * 8) * 64));
        }
    };

    const int nt = K >> 6;
    STAGE(0, 0);

    for (int t = 0; t < nt; ++t) {
        __syncthreads();                       // stage(t) landed; buf[(t+1)&1] free
        if (t + 1 < nt) STAGE((t + 1) << 6, (t + 1) & 1);
        const char* Asb = (const char*)AB + (t & 1) * 32768;
        const char* Bsb = Asb + 16384;
        #pragma unroll
        for (int ks = 0; ks < 2; ++ks) {
            bf16x8 af[4], bfr[4];
            #pragma unroll
            for (int i = 0; i < 4; ++i) {
                int row = wr + i * 16 + (l & 15);
                int slot = (ks * 4 + (l >> 4)) ^ (row & 7);
                af[i] = *(const bf16x8*)(Asb + row * 128 + slot * 16);
            }
            #pragma unroll
            for (int j = 0; j < 4; ++j) {
                int row = wc + j * 16 + (l & 15);
                int slot = (ks * 4 + (l >> 4)) ^ (row & 7);
                bfr[j] = *(const bf16x8*)(Bsb + row * 128 + slot * 16);
            }
            __builtin_amdgcn_s_setprio(1);
            #pragma unroll
            for (int i = 0; i < 4; ++i)
                #pragma unroll
                for (int j = 0; j < 4; ++j)
                    acc[i][j] = __builtin_amdgcn_mfma_f32_16x16x32_bf16(af[i], bfr[j], acc[i][j], 0, 0, 0);
            __builtin_amdgcn_s_setprio(0);
        }
    }

    // Epilogue. C/D layout: col = lane&15, row = (lane>>4)*4 + reg.
    if (MODE == 0) {
        #pragma unroll
        for (int i = 0; i < 4; ++i)
            #pragma unroll
            for (int j = 0; j < 4; ++j)
                #pragma unroll
                for (int r = 0; r < 4; ++r) {
                    int row = m0 + wr + i * 16 + (l >> 4) * 4 + r;
                    int col = n0 + wc + j * 16 + (l & 15);
                    C[(size_t)row * N + col] = acc[i][j][r];
                }
    } else {
        const int seg = (n0 + wc) >> 10;  // 0=Q 1=K 2=V (block-uniform)
        #pragma unroll
        for (int i = 0; i < 4; ++i) {
            const int mbase = m0 + wr + i * 16 + (l >> 4) * 4;
            #pragma unroll
            for (int j = 0; j < 4; ++j) {
                const int n = n0 + wc + j * 16 + (l & 15);
                const int h = (n >> 6) & 15;
                const int d = n & 63;
                if (seg < 2) {
                    unsigned short* dst = (seg == 0) ? Qd : Kd;
                    const int de = d & ~1;
                    const float freq = __expf((float)de * (-9.210340371976184f / 64.f));
                    #pragma unroll
                    for (int r = 0; r < 4; ++r) {
                        const int m = mbase + r;
                        const int b = m >> 11, s = m & 2047;
                        float v = acc[i][j][r];
                        float p2 = __shfl_xor(v, 1);   // partner column of the RoPE pair
                        float ang = (float)pos[m] * freq;
                        float sn, cs;
                        __sincosf(ang, &sn, &cs);
                        float res = ((l & 1) == 0) ? (v * cs - p2 * sn) : (p2 * sn + v * cs);
                        if (seg == 0) res *= 0.18033688011112042f;  // 0.125*log2(e)
                        dst[((size_t)(b * NHEADS + h) * SLEN + s) * DK + d] = f2bf(res);
                    }
                } else {
                    const int b = mbase >> 11, s0 = mbase & 2047;
                    ushort4 o;
                    o.x = f2bf(acc[i][j][0]); o.y = f2bf(acc[i][j][1]);
                    o.z = f2bf(acc[i][j][2]); o.w = f2bf(acc[i][j][3]);
                    *(ushort4*)&Vtd[((size_t)(b * NHEADS + h) * DK + d) * SLEN + s0] = o;
                }
            }
        }
    }
}

// ---------------------------------------------------------------------------
// MFMA flash attention v3: swapped QK^T (S^T), O^T-form PV, lane-local softmax,
// double-buffered K/V LDS (2-phase rotation). Block = 64 q-rows of one (b,h),
// 4 waves, KV tile 128. XCD-clustered bh (4 bh per XCD -> 2 MB K/V in L2) with
// heavy/light qt interleave per bh for uniform retirement.
// ---------------------------------------------------------------------------
__global__ __launch_bounds__(256)
void attn_mfma(const unsigned short* __restrict__ Q,
               const unsigned short* __restrict__ K,
               const unsigned short* __restrict__ Vt,
               unsigned short* __restrict__ Oa)
{
    __shared__ char smem[65536];   // [buf][Ks 16KB | Vs 16KB]
    const int tid = threadIdx.x;
    const int w = tid >> 6, l = tid & 63;
    const int g = l >> 4, q15 = l & 15;

    const int id = blockIdx.x;
    const int nid = (id & 7) * 128 + (id >> 3);   // XCD-bijective (1024 % 8 == 0)
    const int bh = nid >> 5;
    const int j = nid & 31;
    const int qt = (j & 1) ? ((j - 1) >> 1) : (31 - (j >> 1));
    const int nkt = (qt + 2) >> 1;   // ceil((qt*64+64)/128)

    const unsigned short* Qb = Q + (size_t)bh * SLEN * DK;
    const unsigned short* Kb = K + (size_t)bh * SLEN * DK;
    const unsigned short* Vb = Vt + (size_t)bh * DK * SLEN;

    const int q0 = qt * 64 + w * 16;
    const int q_g = q0 + q15;

    bf16x8 qf[2];
    #pragma unroll
    for (int ks = 0; ks < 2; ++ks)
        qf[ks] = *(const bf16x8*)(Qb + (size_t)(q0 + q15) * DK + ks * 32 + g * 8);

    float m = -1e30f, lsum = 0.f;
    f32x4 oacc[4] = {};

    // P-exchange source lanes: dest dword t reads from group 2*(g&1) + (t>>1)
    const int srcA = q15 + 32 * (g & 1);
    const int srcB = srcA + 16;

    const int lr8 = l >> 3, lp8 = l & 7;
    const int lr4 = l >> 4, lp16 = l & 15;

    auto STAGE = [&](int kt, int buf) {
        unsigned short* Ksd = (unsigned short*)(smem + buf * 32768);
        unsigned short* Vsd = (unsigned short*)(smem + buf * 32768 + 16384);
        #pragma unroll
        for (int i = 0; i < 4; ++i) {
            int row = w * 32 + i * 8 + lr8;
            gload16(Kb + (size_t)(kt * KVB + row) * DK + ((lp8 ^ (row & 7)) * 8),
                    (void*)(Ksd + (w * 32 + i * 8) * DK));
        }
        #pragma unroll
        for (int i = 0; i < 4; ++i) {
            int row = w * 16 + i * 4 + lr4;
            gload16(Vb + (size_t)row * SLEN + kt * KVB + ((lp16 ^ (row & 7)) * 8),
                    (void*)(Vsd + (w * 16 + i * 4) * KVB));
        }
    };

    STAGE(0, 0);

    for (int kt = 0; kt < nkt; ++kt) {
        __syncthreads();                         // stage(kt) landed; other buf free
        if (kt + 1 < nkt) STAGE(kt + 1, (kt + 1) & 1);
        const char* Ksb = smem + (kt & 1) * 32768;
        const char* Vsb = Ksb + 16384;

        // S^T = K · Q (Q as B-operand): sacc[cb] rows = kpos, col = q
        f32x4 sacc[8] = {};
        __builtin_amdgcn_s_setprio(1);
        #pragma unroll
        for (int ks = 0; ks < 2; ++ks)
            #pragma unroll
            for (int cb = 0; cb < 8; ++cb) {
                int row = cb * 16 + q15;
                int slot = (ks * 4 + g) ^ (row & 7);
                bf16x8 kf = *(const bf16x8*)(Ksb + row * 128 + slot * 16);
                sacc[cb] = __builtin_amdgcn_mfma_f32_16x16x32_bf16(kf, qf[ks], sacc[cb], 0, 0, 0);
            }
        __builtin_amdgcn_s_setprio(0);

        // causal mask: only the last tile can touch the diagonal
        if (kt == nkt - 1) {
            const int kb = kt * KVB + g * 4;
            #pragma unroll
            for (int cb = 0; cb < 8; ++cb)
                #pragma unroll
                for (int r = 0; r < 4; ++r)
                    if (kb + cb * 16 + r > q_g) sacc[cb][r] = -1e30f;
        }

        // lane-local softmax (scores already in log2 domain)
        float mx = -1e30f;
        #pragma unroll
        for (int cb = 0; cb < 8; ++cb)
            #pragma unroll
            for (int r = 0; r < 4; ++r) mx = fmaxf(mx, sacc[cb][r]);
        mx = fmaxf(mx, __shfl_xor(mx, 16));
        mx = fmaxf(mx, __shfl_xor(mx, 32));

        if (mx > m + 6.0f) {          // defer-max: skip rescale unless max grew
            float corr = EXP2(m - mx);
            m = mx;
            lsum *= corr;
            #pragma unroll
            for (int db = 0; db < 4; ++db)
                #pragma unroll
                for (int r = 0; r < 4; ++r) oacc[db][r] *= corr;
        }

        float ps = 0.f;
        #pragma unroll
        for (int cb = 0; cb < 8; ++cb)
            #pragma unroll
            for (int r = 0; r < 4; ++r) {
                float e = EXP2(sacc[cb][r] - m);
                sacc[cb][r] = e;
                ps += e;
            }
        ps += __shfl_xor(ps, 16);
        ps += __shfl_xor(ps, 32);
        lsum += ps;

        // pack P to bf16 dwords: pk[cb][u] = {P[k=cb*16+g*4+2u], [+1]}
        unsigned pk[8][2];
        #pragma unroll
        for (int cb = 0; cb < 8; ++cb) {
            pk[cb][0] = cvtpk(sacc[cb][0], sacc[cb][1]);
            pk[cb][1] = cvtpk(sacc[cb][2], sacc[cb][3]);
        }

        // O^T += V^T · P^T  (A = Vs rows d, B = P^T built by register exchange)
        #pragma unroll
        for (int ks2 = 0; ks2 < 4; ++ks2) {
            unsigned y0 = __shfl((int)pk[2 * ks2][0], srcA);
            unsigned y1 = __shfl((int)pk[2 * ks2][1], srcA);
            unsigned y2 = __shfl((int)pk[2 * ks2][0], srcB);
            unsigned y3 = __shfl((int)pk[2 * ks2][1], srcB);
            unsigned z0 = __shfl((int)pk[2 * ks2 + 1][0], srcA);
            unsigned z1 = __shfl((int)pk[2 * ks2 + 1][1], srcA);
            unsigned z2 = __shfl((int)pk[2 * ks2 + 1][0], srcB);
            unsigned z3 = __shfl((int)pk[2 * ks2 + 1][1], srcB);
            union { unsigned u[4]; bf16x8 v; } pf;
            const bool lo = (g < 2);
            pf.u[0] = lo ? y0 : z0;
            pf.u[1] = lo ? y1 : z1;
            pf.u[2] = lo ? y2 : z2;
            pf.u[3] = lo ? y3 : z3;
            __builtin_amdgcn_s_setprio(1);
            #pragma unroll
            for (int db = 0; db < 4; ++db) {
                int row = db * 16 + q15;
                int slot = (ks2 * 4 + g) ^ (row & 7);
                bf16x8 vf = *(const bf16x8*)(Vsb + row * 256 + slot * 16);
                oacc[db] = __builtin_amdgcn_mfma_f32_16x16x32_bf16(vf, pf.v, oacc[db], 0, 0, 0);
            }
            __builtin_amdgcn_s_setprio(0);
        }
    }
    __syncthreads();   // all waves done with K/V buffers

    // epilogue: O^T -> O via LDS transpose (Os aliases smem; swizzled, b64 writes)
    unsigned short* Os = (unsigned short*)smem;   // [64 q][64 d]
    const float inv = 1.f / lsum;
    const int ql = w * 16 + q15;
    #pragma unroll
    for (int db = 0; db < 4; ++db) {
        const int d0 = db * 16 + g * 4;
        uint2 pv;
        pv.x = cvtpk(oacc[db][0] * inv, oacc[db][1] * inv);
        pv.y = cvtpk(oacc[db][2] * inv, oacc[db][3] * inv);
        int byte = ql * 128 + ((d0 * 2) ^ ((ql & 7) << 4));
        *(uint2*)((char*)Os + byte) = pv;
    }
    __syncthreads();

    const int b = bh >> 4, h = bh & 15;
    #pragma unroll
    for (int i = 0; i < 2; ++i) {
        int qp = w * 16 + i * 8 + (l >> 3);
        int c = l & 7;
        uint4 vv = *(const uint4*)((const char*)Os + qp * 128 + ((c ^ (qp & 7)) << 4));
        int srow = qt * 64 + qp;
        *(uint4*)&Oa[((size_t)(b * SLEN + srow)) * DMODEL + h * DK + c * 8] = vv;
    }
}

extern "C" void kernel_launch(void* const* d_in, const int* in_sizes, int n_in,
                              void* d_out, int out_size, void* d_ws, size_t ws_size,
                              hipStream_t stream)
{
    const float* x  = (const float*)d_in[0];
    const float* Wq = (const float*)d_in[1];
    const float* Wk = (const float*)d_in[2];
    const float* Wv = (const float*)d_in[3];
    const float* Wo = (const float*)d_in[4];
    const int*  pos = (const int*)d_in[5];
    float* out = (float*)d_out;

    char* ws = (char*)d_ws;
    const size_t MB = 1024 * 1024;
    unsigned short* xb   = (unsigned short*)(ws);             // 8 MB
    unsigned short* Wcat = (unsigned short*)(ws + 8 * MB);    // 6 MB
    unsigned short* Wot  = (unsigned short*)(ws + 14 * MB);   // 2 MB
    unsigned short* Qws  = (unsigned short*)(ws + 16 * MB);   // 8 MB [32][2048][64]
    unsigned short* Kws  = (unsigned short*)(ws + 24 * MB);   // 8 MB [32][2048][64]
    unsigned short* Vtws = (unsigned short*)(ws + 32 * MB);   // 8 MB [32][64][2048]
    unsigned short* attb = (unsigned short*)(ws + 40 * MB);   // 8 MB [4096][1024]

    convert_bf16<<<4096, 256, 0, stream>>>(x, xb, M_TOT * DMODEL / 4);
    transpose_w<<<dim3(16, 16), 256, 0, stream>>>(Wq, Wcat);
    transpose_w<<<dim3(16, 16), 256, 0, stream>>>(Wk, Wcat + 1024 * 1024);
    transpose_w<<<dim3(16, 16), 256, 0, stream>>>(Wv, Wcat + 2 * 1024 * 1024);
    transpose_w<<<dim3(16, 16), 256, 0, stream>>>(Wo, Wot);

    gemm_mfma<1><<<dim3(NQKV / 128, M_TOT / 128), 256, 0, stream>>>(
        xb, Wcat, nullptr, Qws, Kws, Vtws, pos, NQKV, DMODEL);

    attn_mfma<<<1024, 256, 0, stream>>>(Qws, Kws, Vtws, attb);

    gemm_mfma<0><<<dim3(DMODEL / 128, M_TOT / 128), 256, 0, stream>>>(
        attb, Wot, out, nullptr, nullptr, nullptr, nullptr, DMODEL, DMODEL);
}

// Round 6
// 125.271 us; speedup vs baseline: 10.6212x; 1.1272x over previous
//
#include <hip/hip_runtime.h>
#include <math.h>

#define SLEN 2048
#define DMODEL 1024
#define NHEADS 16
#define DK 64
#define NBATCH 2
#define M_TOT (NBATCH * SLEN)   // 4096
#define NQKV (3 * DMODEL)       // 3072

typedef __bf16 bf16x8 __attribute__((ext_vector_type(8)));
typedef float f32x4 __attribute__((ext_vector_type(4)));
typedef float f32x16 __attribute__((ext_vector_type(16)));

// f32 -> bf16 round-to-nearest-even
static __device__ __forceinline__ unsigned short f2bf(float f) {
    unsigned int u = __float_as_uint(f);
    u += 0x7fffu + ((u >> 16) & 1u);
    return (unsigned short)(u >> 16);
}

// pack two f32 -> bf16x2 dword (lo = a, hi = b)
static __device__ __forceinline__ unsigned cvtpk(float a, float b) {
    unsigned r;
    asm("v_cvt_pk_bf16_f32 %0, %1, %2" : "=v"(r) : "v"(a), "v"(b));
    return r;
}

#if __has_builtin(__builtin_amdgcn_exp2f)
#define EXP2(x) __builtin_amdgcn_exp2f(x)
#else
#define EXP2(x) exp2f(x)
#endif

// async global->LDS, 16 B per lane. lds dest is wave-uniform base + lane*16.
static __device__ __forceinline__ void gload16(const void* g, void* l) {
    __builtin_amdgcn_global_load_lds(
        (const __attribute__((address_space(1))) unsigned int*)g,
        (__attribute__((address_space(3))) unsigned int*)l, 16, 0, 0);
}

// ---------------------------------------------------------------------------
// x f32 -> bf16 (flat copy)
// ---------------------------------------------------------------------------
__global__ __launch_bounds__(256)
void convert_bf16(const float* __restrict__ X, unsigned short* __restrict__ Xb, int n4)
{
    int i = blockIdx.x * 256 + threadIdx.x;
    if (i < n4) {
        float4 v = *(const float4*)&X[(size_t)i * 4];
        ushort4 o;
        o.x = f2bf(v.x); o.y = f2bf(v.y); o.z = f2bf(v.z); o.w = f2bf(v.w);
        *(ushort4*)&Xb[(size_t)i * 4] = o;
    }
}

// ---------------------------------------------------------------------------
// W [1024][1024] f32 -> Wt [N][K] bf16 (transposed, so K is contiguous)
// ---------------------------------------------------------------------------
__global__ __launch_bounds__(256)
void transpose_w(const float* __restrict__ W, unsigned short* __restrict__ Wt)
{
    __shared__ float t[64][65];
    const int tid = threadIdx.x;
    const int c0 = blockIdx.x * 64, r0 = blockIdx.y * 64;
    const int tr = tid >> 4, tc = (tid & 15) * 4;
    #pragma unroll
    for (int rr = 0; rr < 4; ++rr) {
        int row = rr * 16 + tr;
        float4 v = *(const float4*)&W[(size_t)(r0 + row) * DMODEL + c0 + tc];
        t[row][tc + 0] = v.x; t[row][tc + 1] = v.y;
        t[row][tc + 2] = v.z; t[row][tc + 3] = v.w;
    }
    __syncthreads();
    #pragma unroll
    for (int rr = 0; rr < 4; ++rr) {
        int orow = rr * 16 + tr;
        ushort4 o;
        o.x = f2bf(t[tc + 0][orow]);
        o.y = f2bf(t[tc + 1][orow]);
        o.z = f2bf(t[tc + 2][orow]);
        o.w = f2bf(t[tc + 3][orow]);
        *(ushort4*)&Wt[(size_t)(c0 + orow) * DMODEL + r0 + tc] = o;
    }
}

// ---------------------------------------------------------------------------
// bf16 MFMA GEMM: C[M,N] = A[M,K] @ Bt[N,K]^T.  BM=BN=128, BK=64, 4 waves.
// Double-buffered LDS 2-phase rotation.
// MODE 0: C f32 [M][N]          (att @ Wo -> d_out)
// MODE 1: N=3072 QKV fused; Q,K: RoPE; Q scaled by 0.125*log2e -> [bh][s][64];
//         V -> [bh][64][s] (transposed)
// ---------------------------------------------------------------------------
template<int MODE>
__global__ __launch_bounds__(256)
void gemm_mfma(const unsigned short* __restrict__ A,
               const unsigned short* __restrict__ Bt,
               float* __restrict__ C,
               unsigned short* __restrict__ Qd,
               unsigned short* __restrict__ Kd,
               unsigned short* __restrict__ Vtd,
               const int* __restrict__ pos,
               int N, int K)
{
    __shared__ unsigned short AB[2 * 2 * 128 * 64];   // [buf][A/B][128][64], 64 KB
    const int tid = threadIdx.x;
    const int w = tid >> 6, l = tid & 63;
    const int m0 = blockIdx.y * 128, n0 = blockIdx.x * 128;
    const int wr = (w >> 1) * 64, wc = (w & 1) * 64;
    const int lr = l >> 3, lp = l & 7;

    f32x4 acc[4][4] = {};

    auto STAGE = [&](int k0, int buf) {
        unsigned short* Asd = AB + buf * (2 * 128 * 64);
        unsigned short* Bsd = Asd + 128 * 64;
        #pragma unroll
        for (int i = 0; i < 4; ++i) {
            int row = w * 32 + i * 8 + lr;
            int s = lp ^ (row & 7);
            gload16(A  + (size_t)(m0 + row) * K + k0 + s * 8, (void*)(Asd + (w * 32 + i * 8) * 64));
            gload16(Bt + (size_t)(n0 + row) * K + k0 + s * 8, (void*)(Bsd + (w * 32 + i * 8) * 64));
        }
    };

    const int nt = K >> 6;
    STAGE(0, 0);

    for (int t = 0; t < nt; ++t) {
        __syncthreads();                       // stage(t) landed; buf[(t+1)&1] free
        if (t + 1 < nt) STAGE((t + 1) << 6, (t + 1) & 1);
        const char* Asb = (const char*)AB + (t & 1) * 32768;
        const char* Bsb = Asb + 16384;
        #pragma unroll
        for (int ks = 0; ks < 2; ++ks) {
            bf16x8 af[4], bfr[4];
            #pragma unroll
            for (int i = 0; i < 4; ++i) {
                int row = wr + i * 16 + (l & 15);
                int slot = (ks * 4 + (l >> 4)) ^ (row & 7);
                af[i] = *(const bf16x8*)(Asb + row * 128 + slot * 16);
            }
            #pragma unroll
            for (int j = 0; j < 4; ++j) {
                int row = wc + j * 16 + (l & 15);
                int slot = (ks * 4 + (l >> 4)) ^ (row & 7);
                bfr[j] = *(const bf16x8*)(Bsb + row * 128 + slot * 16);
            }
            __builtin_amdgcn_s_setprio(1);
            #pragma unroll
            for (int i = 0; i < 4; ++i)
                #pragma unroll
                for (int j = 0; j < 4; ++j)
                    acc[i][j] = __builtin_amdgcn_mfma_f32_16x16x32_bf16(af[i], bfr[j], acc[i][j], 0, 0, 0);
            __builtin_amdgcn_s_setprio(0);
        }
    }

    // Epilogue. C/D layout: col = lane&15, row = (lane>>4)*4 + reg.
    if (MODE == 0) {
        #pragma unroll
        for (int i = 0; i < 4; ++i)
            #pragma unroll
            for (int j = 0; j < 4; ++j)
                #pragma unroll
                for (int r = 0; r < 4; ++r) {
                    int row = m0 + wr + i * 16 + (l >> 4) * 4 + r;
                    int col = n0 + wc + j * 16 + (l & 15);
                    C[(size_t)row * N + col] = acc[i][j][r];
                }
    } else {
        const int seg = (n0 + wc) >> 10;  // 0=Q 1=K 2=V (block-uniform)
        #pragma unroll
        for (int i = 0; i < 4; ++i) {
            const int mbase = m0 + wr + i * 16 + (l >> 4) * 4;
            #pragma unroll
            for (int j = 0; j < 4; ++j) {
                const int n = n0 + wc + j * 16 + (l & 15);
                const int h = (n >> 6) & 15;
                const int d = n & 63;
                if (seg < 2) {
                    unsigned short* dst = (seg == 0) ? Qd : Kd;
                    const int de = d & ~1;
                    const float freq = __expf((float)de * (-9.210340371976184f / 64.f));
                    #pragma unroll
                    for (int r = 0; r < 4; ++r) {
                        const int m = mbase + r;
                        const int b = m >> 11, s = m & 2047;
                        float v = acc[i][j][r];
                        float p2 = __shfl_xor(v, 1);   // partner column of the RoPE pair
                        float ang = (float)pos[m] * freq;
                        float sn, cs;
                        __sincosf(ang, &sn, &cs);
                        float res = ((l & 1) == 0) ? (v * cs - p2 * sn) : (p2 * sn + v * cs);
                        if (seg == 0) res *= 0.18033688011112042f;  // 0.125*log2(e)
                        dst[((size_t)(b * NHEADS + h) * SLEN + s) * DK + d] = f2bf(res);
                    }
                } else {
                    const int b = mbase >> 11, s0 = mbase & 2047;
                    ushort4 o;
                    o.x = f2bf(acc[i][j][0]); o.y = f2bf(acc[i][j][1]);
                    o.z = f2bf(acc[i][j][2]); o.w = f2bf(acc[i][j][3]);
                    *(ushort4*)&Vtd[((size_t)(b * NHEADS + h) * DK + d) * SLEN + s0] = o;
                }
            }
        }
    }
}

// ---------------------------------------------------------------------------
// MFMA flash attention v4b: 32x32x16 MFMA. Block = 128 q of one (b,h), 4 waves
// (wave w: q-cols w*32..+31), KV tile 64, LDS dbuf 32 KB.
// S^T = K·Q: lane (h=l>>5, c31=l&31) owns col q = qw+c31, kv rows
// mt*32 + (r&3)+8*(r>>2)+4h. P^T -> PV B-frag via 4 cvt_pk + 4 shfl_xor(32)
// + 4 selects per 16-k chunk (explicitly derived, no permlane semantics bet):
//   d0=[pk0_L|pk2_L] d1=[pk1_L|pk3_L] d2=[pk0_H|pk2_H] d3=[pk1_H|pk3_H].
// O^T[d][q] accumulated; transposed once via LDS at the end.
// ---------------------------------------------------------------------------
__global__ __launch_bounds__(256)
void attn_mfma(const unsigned short* __restrict__ Q,
               const unsigned short* __restrict__ K,
               const unsigned short* __restrict__ Vt,
               unsigned short* __restrict__ Oa)
{
    __shared__ char smem[32768];   // [buf 16KB][ K 8KB | V^T 8KB ]
    const int tid = threadIdx.x;
    const int w = tid >> 6, l = tid & 63;
    const int h = l >> 5, c31 = l & 31;

    const int id = blockIdx.x;
    const int nid = (id & 7) * 64 + (id >> 3);    // XCD-bijective (512 % 8 == 0)
    const int bh = nid >> 4;
    const int j5 = nid & 15;
    const int a5 = (j5 & 1) ? ((j5 - 1) >> 1) : (15 - (j5 >> 1));
    const int qt = ((bh >> 1) & 1) ? (15 - a5) : a5;
    const int nkt = 2 * qt + 2;
    const int ktmax = 2 * qt + (w >> 1);   // wave's last non-fully-masked tile

    const unsigned short* Qb = Q + (size_t)bh * SLEN * DK;
    const unsigned short* Kb = K + (size_t)bh * SLEN * DK;
    const unsigned short* Vb = Vt + (size_t)bh * DK * SLEN;

    const int qw = qt * 128 + w * 32;
    const int q_g = qw + c31;

    // Q B-frags (B col = q, k = kb*16 + h*8): 4 x 16B global loads
    bf16x8 qf[4];
    #pragma unroll
    for (int kb = 0; kb < 4; ++kb)
        qf[kb] = *(const bf16x8*)(Qb + (size_t)q_g * DK + kb * 16 + h * 8);

    float m = -1e30f, lsum = 0.f;
    f32x16 oacc[2] = {};

    const int srow = tid >> 3;    // staging: 32 rows/pass, 8 slots
    const int sslot = tid & 7;

    auto STAGE = [&](int kt, int buf) {
        char* base = smem + buf * 16384;
        #pragma unroll
        for (int i = 0; i < 2; ++i) {
            int kv = i * 32 + srow;
            gload16(Kb + (size_t)(kt * 64 + kv) * DK + (sslot ^ (kv & 7)) * 8,
                    (void*)(base + i * 4096 + w * 1024));
        }
        #pragma unroll
        for (int i = 0; i < 2; ++i) {
            int d = i * 32 + srow;
            gload16(Vb + (size_t)d * SLEN + kt * 64 + (sslot ^ (d & 7)) * 8,
                    (void*)(base + 8192 + i * 4096 + w * 1024));
        }
    };

    STAGE(0, 0);

    for (int kt = 0; kt < nkt; ++kt) {
        __syncthreads();                        // stage(kt) landed; other buf free
        if (kt + 1 < nkt) STAGE(kt + 1, (kt + 1) & 1);

        if (kt <= ktmax) {
            const char* Kbuf = smem + (kt & 1) * 16384;
            const char* Vbuf = Kbuf + 8192;

            // S^T = K · Q
            f32x16 sacc[2] = {};
            __builtin_amdgcn_s_setprio(1);
            #pragma unroll
            for (int kb = 0; kb < 4; ++kb)
                #pragma unroll
                for (int mt = 0; mt < 2; ++mt) {
                    int row = mt * 32 + c31;
                    int slot = (kb * 2 + h) ^ (row & 7);
                    bf16x8 kf = *(const bf16x8*)(Kbuf + row * 128 + slot * 16);
                    sacc[mt] = __builtin_amdgcn_mfma_f32_32x32x16_bf16(kf, qf[kb], sacc[mt], 0, 0, 0);
                }
            __builtin_amdgcn_s_setprio(0);

            // causal mask (diagonal tile only)
            if (kt == ktmax) {
                #pragma unroll
                for (int mt = 0; mt < 2; ++mt)
                    #pragma unroll
                    for (int r = 0; r < 16; ++r) {
                        int kv = kt * 64 + mt * 32 + (r & 3) + 8 * (r >> 2) + 4 * h;
                        if (kv > q_g) sacc[mt][r] = -1e30f;
                    }
            }

            // column max: local tree + lane^32 exchange
            float t16[16];
            #pragma unroll
            for (int r = 0; r < 16; ++r) t16[r] = fmaxf(sacc[0][r], sacc[1][r]);
            #pragma unroll
            for (int s = 8; s > 0; s >>= 1)
                #pragma unroll
                for (int r = 0; r < s; ++r) t16[r] = fmaxf(t16[r], t16[r + s]);
            float mx = t16[0];
            mx = fmaxf(mx, __shfl_xor(mx, 32));

            if (mx > m + 6.0f) {        // defer-max
                float corr = EXP2(m - mx);
                m = mx;
                lsum *= corr;
                oacc[0] *= corr;
                oacc[1] *= corr;
            }

            // P = exp2(S - m), in place; column sum
            #pragma unroll
            for (int mt = 0; mt < 2; ++mt)
                #pragma unroll
                for (int r = 0; r < 16; ++r)
                    sacc[mt][r] = EXP2(sacc[mt][r] - m);
            #pragma unroll
            for (int r = 0; r < 16; ++r) t16[r] = sacc[0][r] + sacc[1][r];
            #pragma unroll
            for (int s = 8; s > 0; s >>= 1)
                #pragma unroll
                for (int r = 0; r < s; ++r) t16[r] += t16[r + s];
            float ps = t16[0];
            ps += __shfl_xor(ps, 32);
            lsum += ps;

            // O^T += V^T · P^T ; B-frag per 16-k chunk:
            //   own pk0..3 = within-chunk kv offsets (0,1)(2,3)(8,9)(10,11) [+4h]
            //   d0=[pk0_L|pk2_L] d1=[pk1_L|pk3_L] d2=[pk0_H|pk2_H] d3=[pk1_H|pk3_H]
            #pragma unroll
            for (int ks = 0; ks < 4; ++ks) {
                const int mt = ks >> 1, rb = (ks & 1) * 8;
                unsigned pk0 = cvtpk(sacc[mt][rb + 0], sacc[mt][rb + 1]);
                unsigned pk1 = cvtpk(sacc[mt][rb + 2], sacc[mt][rb + 3]);
                unsigned pk2 = cvtpk(sacc[mt][rb + 4], sacc[mt][rb + 5]);
                unsigned pk3 = cvtpk(sacc[mt][rb + 6], sacc[mt][rb + 7]);
                unsigned s0 = (unsigned)__shfl_xor((int)pk0, 32);
                unsigned s1 = (unsigned)__shfl_xor((int)pk1, 32);
                unsigned s2 = (unsigned)__shfl_xor((int)pk2, 32);
                unsigned s3 = (unsigned)__shfl_xor((int)pk3, 32);
                union { unsigned u[4]; bf16x8 v; } pf;
                pf.u[0] = (h == 0) ? pk0 : s2;
                pf.u[1] = (h == 0) ? pk1 : s3;
                pf.u[2] = (h == 0) ? s0 : pk2;
                pf.u[3] = (h == 0) ? s1 : pk3;
                __builtin_amdgcn_s_setprio(1);
                #pragma unroll
                for (int mt2 = 0; mt2 < 2; ++mt2) {
                    int row = mt2 * 32 + c31;
                    int slot = (ks * 2 + h) ^ (row & 7);
                    bf16x8 vf = *(const bf16x8*)(Vbuf + row * 128 + slot * 16);
                    oacc[mt2] = __builtin_amdgcn_mfma_f32_32x32x16_bf16(vf, pf.v, oacc[mt2], 0, 0, 0);
                }
                __builtin_amdgcn_s_setprio(0);
            }
        }
    }
    __syncthreads();   // everyone done with K/V buffers

    // epilogue: O^T[d][q] -> Os[128 q][64 d] bf16 (16 KB, swizzled), then store
    unsigned short* Os = (unsigned short*)smem;
    const float inv = 1.f / lsum;
    const int ql = w * 32 + c31;
    #pragma unroll
    for (int mt = 0; mt < 2; ++mt)
        #pragma unroll
        for (int rq = 0; rq < 4; ++rq) {
            uint2 pv;
            pv.x = cvtpk(oacc[mt][rq * 4 + 0] * inv, oacc[mt][rq * 4 + 1] * inv);
            pv.y = cvtpk(oacc[mt][rq * 4 + 2] * inv, oacc[mt][rq * 4 + 3] * inv);
            int dbyte = mt * 64 + rq * 16 + h * 8;
            *(uint2*)((char*)Os + ql * 128 + (dbyte ^ ((ql & 7) << 4))) = pv;
        }
    __syncthreads();

    const int b = bh >> 4, hh = bh & 15;
    const int jj = tid & 7;
    #pragma unroll
    for (int p = 0; p < 4; ++p) {
        int qp = p * 32 + (tid >> 3);
        uint4 vv = *(const uint4*)((const char*)Os + qp * 128 + ((jj ^ (qp & 7)) << 4));
        int srow = qt * 128 + qp;
        *(uint4*)&Oa[((size_t)(b * SLEN + srow)) * DMODEL + hh * DK + jj * 8] = vv;
    }
}

extern "C" void kernel_launch(void* const* d_in, const int* in_sizes, int n_in,
                              void* d_out, int out_size, void* d_ws, size_t ws_size,
                              hipStream_t stream)
{
    const float* x  = (const float*)d_in[0];
    const float* Wq = (const float*)d_in[1];
    const float* Wk = (const float*)d_in[2];
    const float* Wv = (const float*)d_in[3];
    const float* Wo = (const float*)d_in[4];
    const int*  pos = (const int*)d_in[5];
    float* out = (float*)d_out;

    char* ws = (char*)d_ws;
    const size_t MB = 1024 * 1024;
    unsigned short* xb   = (unsigned short*)(ws);             // 8 MB
    unsigned short* Wcat = (unsigned short*)(ws + 8 * MB);    // 6 MB
    unsigned short* Wot  = (unsigned short*)(ws + 14 * MB);   // 2 MB
    unsigned short* Qws  = (unsigned short*)(ws + 16 * MB);   // 8 MB [32][2048][64]
    unsigned short* Kws  = (unsigned short*)(ws + 24 * MB);   // 8 MB [32][2048][64]
    unsigned short* Vtws = (unsigned short*)(ws + 32 * MB);   // 8 MB [32][64][2048]
    unsigned short* attb = (unsigned short*)(ws + 40 * MB);   // 8 MB [4096][1024]

    convert_bf16<<<4096, 256, 0, stream>>>(x, xb, M_TOT * DMODEL / 4);
    transpose_w<<<dim3(16, 16), 256, 0, stream>>>(Wq, Wcat);
    transpose_w<<<dim3(16, 16), 256, 0, stream>>>(Wk, Wcat + 1024 * 1024);
    transpose_w<<<dim3(16, 16), 256, 0, stream>>>(Wv, Wcat + 2 * 1024 * 1024);
    transpose_w<<<dim3(16, 16), 256, 0, stream>>>(Wo, Wot);

    gemm_mfma<1><<<dim3(NQKV / 128, M_TOT / 128), 256, 0, stream>>>(
        xb, Wcat, nullptr, Qws, Kws, Vtws, pos, NQKV, DMODEL);

    attn_mfma<<<512, 256, 0, stream>>>(Qws, Kws, Vtws, attb);

    gemm_mfma<0><<<dim3(DMODEL / 128, M_TOT / 128), 256, 0, stream>>>(
        attb, Wot, out, nullptr, nullptr, nullptr, nullptr, DMODEL, DMODEL);
}